// Round 2
// baseline (3839.188 us; speedup 1.0000x reference)
//
#include <hip/hip_runtime.h>
#include <hip/hip_bf16.h>

#define HH 361
#define WW 720
#define HWP (HH*WW)          // 259920
#define CIN 11
#define CC 32
#define HD 16
#define EE 10
#define LN_EPS 1e-5f
#define SELU_ALPHA 1.6732632423543772f
#define SELU_SCALE 1.0507009873554805f

// bf16 helpers: explicit round-to-nearest-even, no intrinsic ambiguity
static __device__ __forceinline__ unsigned short f2bf(float f) {
    unsigned int u = __float_as_uint(f);
    unsigned int r = (u + 0x7FFFu + ((u >> 16) & 1u)) >> 16;
    return (unsigned short)r;
}
static __device__ __forceinline__ float bf2f(unsigned short s) {
    return __uint_as_float(((unsigned int)s) << 16);
}

// ---------------- zero accumulators ----------------
__global__ void zero_kernel(float* __restrict__ p) {
    int t = blockIdx.x * 256 + threadIdx.x;
    if (t < 40 + HD * EE * EE) p[t] = 0.f;
}

// ---------------- conv 5x5 + SELU + LN partial sums, bf16 x out ----------------
// grid: (12, 23, 10*8), block: (64,4); thread: 4 rows x 4 output channels
__global__ __launch_bounds__(256) void conv_selu_kernel(
    const float* __restrict__ inp, const float* __restrict__ emb_w,
    const float* __restrict__ emb_b, unsigned short* __restrict__ xout,
    float* __restrict__ stats)
{
    __shared__ float wsm[4 * CIN * 5 * 8];  // [u*CIN+ci][kh][kw pad 8]
    __shared__ float bsm[4];
    const int z = blockIdx.z;
    const int e = z >> 3, cog = z & 7;
    for (int t = threadIdx.y * 64 + threadIdx.x; t < 4 * CIN * 25; t += 256) {
        int kw = t % 5; int rest = t / 5; int kh = rest % 5; int uci = rest / 5;
        wsm[(uci * 5 + kh) * 8 + kw] = emb_w[(cog * 4 * CIN + uci) * 25 + kh * 5 + kw];
    }
    if (threadIdx.y == 0 && threadIdx.x < 4) bsm[threadIdx.x] = emb_b[cog * 4 + threadIdx.x];
    __syncthreads();

    const int w  = blockIdx.x * 64 + threadIdx.x;
    const int h0 = blockIdx.y * 16 + threadIdx.y * 4;
    const bool active = (w < WW);

    int wl[5];
    if (active) {
        #pragma unroll
        for (int d = 0; d < 5; ++d) {
            int ww = w + d - 2; if (ww < 0) ww += WW; if (ww >= WW) ww -= WW; wl[d] = ww;
        }
    }
    float acc[4][4];
    #pragma unroll
    for (int hs = 0; hs < 4; ++hs)
        #pragma unroll
        for (int u = 0; u < 4; ++u) acc[hs][u] = bsm[u];

    if (active) {
        for (int ci = 0; ci < CIN; ++ci) {
            const float* ip = inp + ((size_t)(e * CIN + ci)) * HWP;
            float in[8][5];
            #pragma unroll
            for (int r = 0; r < 8; ++r) {
                int hh = h0 + r - 2;
                bool v = (hh >= 0 && hh < HH);
                const float* rp = ip + (size_t)hh * WW;
                #pragma unroll
                for (int d = 0; d < 5; ++d) in[r][d] = v ? rp[wl[d]] : 0.f;
            }
            #pragma unroll
            for (int u = 0; u < 4; ++u) {
                #pragma unroll
                for (int kh = 0; kh < 5; ++kh) {
                    const float* wp = &wsm[((u * CIN + ci) * 5 + kh) * 8];
                    float w0 = wp[0], w1 = wp[1], w2 = wp[2], w3 = wp[3], w4 = wp[4];
                    #pragma unroll
                    for (int hs = 0; hs < 4; ++hs) {
                        acc[hs][u] = fmaf(in[hs + kh][0], w0, acc[hs][u]);
                        acc[hs][u] = fmaf(in[hs + kh][1], w1, acc[hs][u]);
                        acc[hs][u] = fmaf(in[hs + kh][2], w2, acc[hs][u]);
                        acc[hs][u] = fmaf(in[hs + kh][3], w3, acc[hs][u]);
                        acc[hs][u] = fmaf(in[hs + kh][4], w4, acc[hs][u]);
                    }
                }
            }
        }
    }

    float s = 0.f, s2 = 0.f;
    #pragma unroll
    for (int hs = 0; hs < 4; ++hs) {
        int h = h0 + hs;
        if (active && h < HH) {
            #pragma unroll
            for (int u = 0; u < 4; ++u) {
                float v = acc[hs][u];
                v = v > 0.f ? SELU_SCALE * v : SELU_SCALE * SELU_ALPHA * expm1f(v);
                xout[((size_t)(e * CC + cog * 4 + u)) * HWP + (size_t)h * WW + w] = f2bf(v);
                s += v; s2 = fmaf(v, v, s2);
            }
        }
    }
    #pragma unroll
    for (int off = 32; off; off >>= 1) { s += __shfl_down(s, off); s2 += __shfl_down(s2, off); }
    __shared__ float red[8];
    int tid = threadIdx.y * 64 + threadIdx.x;
    if ((tid & 63) == 0) { red[tid >> 6] = s; red[4 + (tid >> 6)] = s2; }
    __syncthreads();
    if (tid == 0) {
        atomicAdd(&stats[e], red[0] + red[1] + red[2] + red[3]);
        atomicAdd(&stats[EE + e], red[4] + red[5] + red[6] + red[7]);
    }
}

// ---------------- finalize LN stats ----------------
__global__ void ln_stats_kernel(float* __restrict__ stats) {
    int e = threadIdx.x;
    if (e < EE) {
        const float N = (float)CC * (float)HWP;
        float mu = stats[e] / N;
        float var = stats[EE + e] / N - mu * mu;
        stats[2 * EE + e] = mu;
        stats[3 * EE + e] = rsqrtf(var + LN_EPS);
    }
}

// ---------------- fused k,q + scores (no kq buffer) ----------------
// grid: (64, 4 head-groups), block 256 (4 waves). Per 64-pixel wave batch:
// each lane computes k,q (4 heads x 10 members) for its pixel, stages to LDS,
// then lanes own (c,i,j) triples and accumulate over the 64 pixels.
__global__ __launch_bounds__(256) void scores_fused_kernel(
    const unsigned short* __restrict__ x, const float* __restrict__ ln_w,
    const float* __restrict__ ln_b, const float* __restrict__ wk,
    const float* __restrict__ wq, const float* __restrict__ stats,
    float* __restrict__ sacc)
{
    const int g = blockIdx.y;  // heads g*4 .. g*4+3
    __shared__ float wks[4 * CC], wqs[4 * CC];
    __shared__ unsigned int stage[4][64][41];  // [wave][pixel-lane][40 dwords data + 1 pad]
    for (int t = threadIdx.x; t < 4 * CC; t += 256) {
        wks[t] = wk[(g * 4 + (t >> 5)) * CC + (t & 31)];
        wqs[t] = wq[(g * 4 + (t >> 5)) * CC + (t & 31)];
    }
    __syncthreads();

    float mu[EE], rs[EE];
    #pragma unroll
    for (int e = 0; e < EE; ++e) { mu[e] = stats[2 * EE + e]; rs[e] = stats[3 * EE + e]; }

    const int wv = threadIdx.x >> 6;
    const int lane = threadIdx.x & 63;
    float acc[7] = {0.f, 0.f, 0.f, 0.f, 0.f, 0.f, 0.f};

    const int nbatch = (HWP + 63) / 64;  // 4062
    const int wid = blockIdx.x * 4 + wv;

    for (int b = wid; b < nbatch; b += 64 * 4) {
        const int pix = b * 64 + lane;
        const bool valid = pix < HWP;
        float lw[CC], lb[CC];
        #pragma unroll
        for (int ch = 0; ch < CC; ++ch) {
            lw[ch] = valid ? ln_w[(size_t)ch * HWP + pix] : 0.f;
            lb[ch] = valid ? ln_b[(size_t)ch * HWP + pix] : 0.f;
        }
        // compute k,q per member, stage as bf16 pairs
        #pragma unroll
        for (int e = 0; e < EE; ++e) {
            float ka[4] = {0.f, 0.f, 0.f, 0.f}, qa[4] = {0.f, 0.f, 0.f, 0.f};
            if (valid) {
                #pragma unroll
                for (int ch = 0; ch < CC; ++ch) {
                    float xv = bf2f(x[((size_t)(e * CC + ch)) * HWP + pix]);
                    float lnv = fmaf((xv - mu[e]) * rs[e], lw[ch], lb[ch]);
                    #pragma unroll
                    for (int c2 = 0; c2 < 4; ++c2) {
                        ka[c2] = fmaf(wks[c2 * CC + ch], lnv, ka[c2]);
                        qa[c2] = fmaf(wqs[c2 * CC + ch], lnv, qa[c2]);
                    }
                }
            }
            #pragma unroll
            for (int c2 = 0; c2 < 4; ++c2) {
                ka[c2] = fmaxf(ka[c2], 0.f);
                qa[c2] = fmaxf(qa[c2], 0.f);
            }
            stage[wv][lane][e * 2]          = (unsigned int)f2bf(ka[0]) | ((unsigned int)f2bf(ka[1]) << 16);
            stage[wv][lane][e * 2 + 1]      = (unsigned int)f2bf(ka[2]) | ((unsigned int)f2bf(ka[3]) << 16);
            stage[wv][lane][20 + e * 2]     = (unsigned int)f2bf(qa[0]) | ((unsigned int)f2bf(qa[1]) << 16);
            stage[wv][lane][20 + e * 2 + 1] = (unsigned int)f2bf(qa[2]) | ((unsigned int)f2bf(qa[3]) << 16);
        }
        // DS ops within a wave retire in order; later reads see the writes above.
        // lane-owned triples T = t*64+lane, T = (j*10+i)*4 + c
        #pragma unroll
        for (int t = 0; t < 7; ++t) {
            int T = t * 64 + lane;
            if (T < 4 * EE * EE) {
                int c2 = T & 3, rest = T >> 2;
                int i = rest % EE, j = rest / EE;
                int koff = i * 4 + c2, qoff = 40 + j * 4 + c2;
                float a = 0.f;
                #pragma unroll 8
                for (int p = 0; p < 64; ++p) {
                    const unsigned short* r = (const unsigned short*)stage[wv][p];
                    a = fmaf(bf2f(r[koff]), bf2f(r[qoff]), a);
                }
                acc[t] += a;
            }
        }
    }
    #pragma unroll
    for (int t = 0; t < 7; ++t) {
        int T = t * 64 + lane;
        if (T < 4 * EE * EE) {
            int c2 = T & 3, rest = T >> 2;
            int i = rest % EE, j = rest / EE;
            int cg = g * 4 + c2;
            atomicAdd(&sacc[(cg * EE + i) * EE + j], acc[t]);
        }
    }
}

// ---------------- softmax over i + fold A = delta + w - 1/E ----------------
__global__ void softmax_kernel(const float* __restrict__ sacc, float* __restrict__ A)
{
    int t = threadIdx.x;
    if (t >= HD * EE) return;
    int c = t / EE, j = t - c * EE;
    const float norm = (float)(1.0 / 509.8234988357398);  // 1/sqrt(361*720)
    float sv[EE];
    float mx = -1e30f;
    #pragma unroll
    for (int i = 0; i < EE; ++i) { sv[i] = sacc[(c * EE + i) * EE + j] * norm; mx = fmaxf(mx, sv[i]); }
    float sum = 0.f;
    #pragma unroll
    for (int i = 0; i < EE; ++i) { sv[i] = expf(sv[i] - mx); sum += sv[i]; }
    float inv = 1.f / sum;
    #pragma unroll
    for (int i = 0; i < EE; ++i) {
        float wgt = sv[i] * inv;
        A[(c * EE + i) * EE + j] = wgt - (1.f / (float)EE) + (i == j ? 1.f : 0.f);
    }
}

// ---------------- fused: v -> tv (via A) -> out proj + residual + relu -> y ----------------
__global__ __launch_bounds__(256) void final_kernel(
    const unsigned short* __restrict__ x, const float* __restrict__ ln_w,
    const float* __restrict__ ln_b, const float* __restrict__ wv,
    const float* __restrict__ wo, const float* __restrict__ bo,
    const float* __restrict__ w_out, const float* __restrict__ b_out,
    const float* __restrict__ stats, const float* __restrict__ A,
    float* __restrict__ y)
{
    __shared__ float wvs[HD * CC], wos[CC * HD], As[HD * EE * EE], bos[CC], wouts[CC];
    for (int t = threadIdx.x; t < HD * CC; t += 256) { wvs[t] = wv[t]; wos[t] = wo[t]; }
    for (int t = threadIdx.x; t < HD * EE * EE; t += 256) As[t] = A[t];
    if (threadIdx.x < CC) { bos[threadIdx.x] = bo[threadIdx.x]; wouts[threadIdx.x] = w_out[threadIdx.x]; }
    __syncthreads();

    int pix = blockIdx.x * 256 + threadIdx.x;
    if (pix >= HWP) return;

    float lw[CC];
    float cb0[HD], cb1[HD];
    #pragma unroll
    for (int c = 0; c < HD; ++c) { cb0[c] = 0.f; cb1[c] = 0.f; }
    #pragma unroll
    for (int ch = 0; ch < CC; ++ch) {
        float w_ = ln_w[(size_t)ch * HWP + pix];
        float b_ = ln_b[(size_t)ch * HWP + pix];
        lw[ch] = w_;
        #pragma unroll
        for (int c = 0; c < HD; ++c) {
            cb0[c] = fmaf(wvs[c * CC + ch], b_, cb0[c]);
            cb1[c] = fmaf(wvs[c * CC + ch], w_, cb1[c]);
        }
    }
    float v[EE][HD];
    for (int e = 0; e < EE; ++e) {
        float mu = stats[2 * EE + e], rs = stats[3 * EE + e];
        float a[HD];
        #pragma unroll
        for (int c = 0; c < HD; ++c) a[c] = 0.f;
        #pragma unroll
        for (int ch = 0; ch < CC; ++ch) {
            float t = bf2f(x[((size_t)(e * CC + ch)) * HWP + pix]) * lw[ch];
            #pragma unroll
            for (int c = 0; c < HD; ++c) a[c] = fmaf(wvs[c * CC + ch], t, a[c]);
        }
        #pragma unroll
        for (int c = 0; c < HD; ++c) v[e][c] = rs * a[c] - mu * rs * cb1[c] + cb0[c];
    }

    const float boutv = b_out[0];
    for (int j = 0; j < EE; ++j) {
        float tv[HD];
        #pragma unroll
        for (int c = 0; c < HD; ++c) {
            float s = 0.f;
            #pragma unroll
            for (int i = 0; i < EE; ++i) s = fmaf(As[(c * EE + i) * EE + j], v[i][c], s);
            tv[c] = s;
        }
        float yv = boutv;
        #pragma unroll
        for (int ch = 0; ch < CC; ++ch) {
            float o = bos[ch] + bf2f(x[((size_t)(j * CC + ch)) * HWP + pix]);
            #pragma unroll
            for (int c = 0; c < HD; ++c) o = fmaf(wos[ch * HD + c], tv[c], o);
            o = fmaxf(o, 0.f);
            yv = fmaf(wouts[ch], o, yv);
        }
        y[(size_t)j * HWP + pix] = yv;
    }
}

extern "C" void kernel_launch(void* const* d_in, const int* in_sizes, int n_in,
                              void* d_out, int out_size, void* d_ws, size_t ws_size,
                              hipStream_t stream)
{
    const float* inp   = (const float*)d_in[0];
    const float* emb_w = (const float*)d_in[1];
    const float* emb_b = (const float*)d_in[2];
    const float* ln_w  = (const float*)d_in[3];
    const float* ln_b  = (const float*)d_in[4];
    const float* wv    = (const float*)d_in[5];
    const float* wk    = (const float*)d_in[6];
    const float* wq    = (const float*)d_in[7];
    const float* wo    = (const float*)d_in[8];
    const float* bo    = (const float*)d_in[9];
    const float* w_out = (const float*)d_in[10];
    const float* b_out = (const float*)d_in[11];
    float* y = (float*)d_out;

    // workspace: bf16 x [E][C][HW] = 166,348,800 B, then f32 stats/sacc/A
    unsigned short* xbuf = (unsigned short*)d_ws;
    float* stats = (float*)((char*)d_ws + (size_t)EE * CC * HWP * 2);
    float* sacc  = stats + 40;
    float* Amat  = sacc + HD * EE * EE;

    zero_kernel<<<7, 256, 0, stream>>>(stats);
    conv_selu_kernel<<<dim3(12, 23, EE * 8), dim3(64, 4), 0, stream>>>(inp, emb_w, emb_b, xbuf, stats);
    ln_stats_kernel<<<1, 64, 0, stream>>>(stats);
    scores_fused_kernel<<<dim3(64, 4), 256, 0, stream>>>(xbuf, ln_w, ln_b, wk, wq, stats, sacc);
    softmax_kernel<<<1, 192, 0, stream>>>(sacc, Amat);
    final_kernel<<<(HWP + 255) / 256, 256, 0, stream>>>(xbuf, ln_w, ln_b, wv, wo, bo,
                                                        w_out, b_out, stats, Amat, y);
}

// Round 3
// 1569.922 us; speedup vs baseline: 2.4455x; 2.4455x over previous
//
#include <hip/hip_runtime.h>
#include <hip/hip_bf16.h>

#define HH 361
#define WW 720
#define HWP (HH*WW)          // 259920
#define CIN 11
#define CC 32
#define HD 16
#define EE 10
#define NBATCH ((HWP + 63) / 64)   // 4062
#define LN_EPS 1e-5f
#define SELU_ALPHA 1.6732632423543772f
#define SELU_SCALE 1.0507009873554805f

// bf16 helpers (round-to-nearest-even pack; cheap unpacks from packed dwords)
static __device__ __forceinline__ unsigned int f2bf(float f) {
    unsigned int u = __float_as_uint(f);
    return (u + 0x7FFFu + ((u >> 16) & 1u)) >> 16;
}
static __device__ __forceinline__ float bflo(unsigned int u) {
    return __uint_as_float(u << 16);
}
static __device__ __forceinline__ float bfhi(unsigned int u) {
    return __uint_as_float(u & 0xffff0000u);
}

// ---------------- zero accumulators ----------------
__global__ void zero_kernel(float* __restrict__ p) {
    int t = blockIdx.x * 256 + threadIdx.x;
    if (t < 40 + HD * EE * EE) p[t] = 0.f;
}

// ---------------- conv 5x5 + SELU + LN partials; x out channel-last bf16 ----------------
// grid (12, 91, 10), block (64,4). thread = 1 pixel, all 32 out channels.
__global__ __launch_bounds__(256) void conv_selu_kernel(
    const float* __restrict__ inp, const float* __restrict__ emb_w,
    const float* __restrict__ emb_b, unsigned short* __restrict__ xout,
    float* __restrict__ stats)
{
    __shared__ float wlds[CIN * 25 * CC];   // [ci][k25][co]  35.2 KB
    __shared__ float bsm[CC];
    __shared__ float red[8];
    const int e = blockIdx.z;
    const int tid = threadIdx.y * 64 + threadIdx.x;
    for (int t = tid; t < CIN * 25 * CC; t += 256) {
        int co = t & 31; int rest = t >> 5; int k25 = rest % 25; int ci = rest / 25;
        wlds[t] = emb_w[(co * CIN + ci) * 25 + k25];
    }
    if (tid < CC) bsm[tid] = emb_b[tid];
    __syncthreads();

    const int w = blockIdx.x * 64 + threadIdx.x;
    const int h = blockIdx.y * 4 + threadIdx.y;
    const bool active = (w < WW) && (h < HH);

    float acc[CC];
    #pragma unroll
    for (int c = 0; c < CC; ++c) acc[c] = bsm[c];

    if (active) {
        int wl[5];
        #pragma unroll
        for (int d = 0; d < 5; ++d) { int ww = w + d - 2; if (ww < 0) ww += WW; if (ww >= WW) ww -= WW; wl[d] = ww; }
        #pragma unroll 1
        for (int ci = 0; ci < CIN; ++ci) {
            const float* ip = inp + ((size_t)(e * CIN + ci)) * HWP;
            float in[5][5];
            #pragma unroll
            for (int r = 0; r < 5; ++r) {
                int hh = h + r - 2;
                bool vld = (hh >= 0) && (hh < HH);
                const float* rp = ip + (size_t)hh * WW;
                #pragma unroll
                for (int d = 0; d < 5; ++d) in[r][d] = vld ? rp[wl[d]] : 0.f;
            }
            const float* wp = &wlds[ci * 25 * CC];
            #pragma unroll
            for (int kh = 0; kh < 5; ++kh) {
                #pragma unroll
                for (int kw = 0; kw < 5; ++kw) {
                    const float iv = in[kh][kw];
                    const float* wr = wp + (kh * 5 + kw) * CC;
                    #pragma unroll
                    for (int c = 0; c < CC; ++c) acc[c] = fmaf(iv, wr[c], acc[c]);
                }
            }
        }
    }

    float s = 0.f, s2 = 0.f;
    if (active) {
        unsigned int pk[16];
        #pragma unroll
        for (int c = 0; c < CC; c += 2) {
            float v0 = acc[c];
            v0 = v0 > 0.f ? SELU_SCALE * v0 : SELU_SCALE * SELU_ALPHA * expm1f(v0);
            float v1 = acc[c + 1];
            v1 = v1 > 0.f ? SELU_SCALE * v1 : SELU_SCALE * SELU_ALPHA * expm1f(v1);
            s += v0 + v1; s2 = fmaf(v0, v0, s2); s2 = fmaf(v1, v1, s2);
            pk[c >> 1] = f2bf(v0) | (f2bf(v1) << 16);
        }
        uint4* dst = (uint4*)(xout + ((size_t)e * HWP + (size_t)h * WW + w) * CC);
        dst[0] = make_uint4(pk[0], pk[1], pk[2], pk[3]);
        dst[1] = make_uint4(pk[4], pk[5], pk[6], pk[7]);
        dst[2] = make_uint4(pk[8], pk[9], pk[10], pk[11]);
        dst[3] = make_uint4(pk[12], pk[13], pk[14], pk[15]);
    }
    #pragma unroll
    for (int off = 32; off; off >>= 1) { s += __shfl_down(s, off); s2 += __shfl_down(s2, off); }
    if ((tid & 63) == 0) { red[tid >> 6] = s; red[4 + (tid >> 6)] = s2; }
    __syncthreads();
    if (tid == 0) {
        atomicAdd(&stats[e], red[0] + red[1] + red[2] + red[3]);
        atomicAdd(&stats[EE + e], red[4] + red[5] + red[6] + red[7]);
    }
}

// ---------------- finalize LN stats ----------------
__global__ void ln_stats_kernel(float* __restrict__ stats) {
    int e = threadIdx.x;
    if (e < EE) {
        const float N = (float)CC * (float)HWP;
        float mu = stats[e] / N;
        float var = stats[EE + e] / N - mu * mu;
        stats[2 * EE + e] = mu;
        stats[3 * EE + e] = rsqrtf(var + LN_EPS);
    }
}

// ---------------- fused k,q + scores ----------------
// grid 1024, block 256 (4 waves = 4 head-quads). Per 64-pixel batch:
// stage phase: wave wv computes k,q for heads wv*4..wv*4+3, all 10 members,
// packs bf16 into stage[64][164]. product phase: 200 threads own (i,j,half).
__global__ __launch_bounds__(256) void scores_fused_kernel(
    const unsigned short* __restrict__ x, const float* __restrict__ ln_w,
    const float* __restrict__ ln_b, const float* __restrict__ wk,
    const float* __restrict__ wq, const float* __restrict__ stats,
    float* __restrict__ sacc)
{
    __shared__ float wksT[CC * HD], wqsT[CC * HD];   // [ch][c]
    __shared__ unsigned int stage[64][164];          // k at [e*8+d], q at [80+e*8+d]
    for (int t = threadIdx.x; t < CC * HD; t += 256) {
        int ch = t >> 4, c = t & 15;
        wksT[t] = wk[c * CC + ch];
        wqsT[t] = wq[c * CC + ch];
    }
    float mu[EE], rs[EE];
    #pragma unroll
    for (int e2 = 0; e2 < EE; ++e2) { mu[e2] = stats[2 * EE + e2]; rs[e2] = stats[3 * EE + e2]; }

    const int wv = threadIdx.x >> 6;
    const int lane = threadIdx.x & 63;
    const int pr = threadIdx.x >> 1;
    const int hf = threadIdx.x & 1;
    const int pi = pr / EE, pj = pr % EE;
    float acc[8] = {0.f,0.f,0.f,0.f,0.f,0.f,0.f,0.f};
    __syncthreads();

    #pragma unroll 1
    for (int b = blockIdx.x; b < NBATCH; b += gridDim.x) {
        const int pix = b * 64 + lane;
        const bool valid = pix < HWP;
        float lw[CC], lb[CC];
        #pragma unroll
        for (int ch = 0; ch < CC; ++ch) {
            lw[ch] = valid ? ln_w[(size_t)ch * HWP + pix] : 0.f;
            lb[ch] = valid ? ln_b[(size_t)ch * HWP + pix] : 0.f;
        }
        #pragma unroll 1
        for (int g = 0; g < 5; ++g) {
            unsigned int xr[2][16];
            #pragma unroll
            for (int eg = 0; eg < 2; ++eg) {
                const int e2 = g * 2 + eg;
                if (valid) {
                    const uint4* xp = (const uint4*)(x + ((size_t)e2 * HWP + pix) * CC);
                    uint4 a0 = xp[0], a1 = xp[1], a2 = xp[2], a3 = xp[3];
                    xr[eg][0]=a0.x; xr[eg][1]=a0.y; xr[eg][2]=a0.z; xr[eg][3]=a0.w;
                    xr[eg][4]=a1.x; xr[eg][5]=a1.y; xr[eg][6]=a1.z; xr[eg][7]=a1.w;
                    xr[eg][8]=a2.x; xr[eg][9]=a2.y; xr[eg][10]=a2.z; xr[eg][11]=a2.w;
                    xr[eg][12]=a3.x; xr[eg][13]=a3.y; xr[eg][14]=a3.z; xr[eg][15]=a3.w;
                } else {
                    #pragma unroll
                    for (int k2 = 0; k2 < 16; ++k2) xr[eg][k2] = 0u;
                }
            }
            float ka[2][4], qa[2][4];
            #pragma unroll
            for (int eg = 0; eg < 2; ++eg)
                #pragma unroll
                for (int u = 0; u < 4; ++u) { ka[eg][u] = 0.f; qa[eg][u] = 0.f; }
            #pragma unroll
            for (int ch = 0; ch < CC; ++ch) {
                const float4 wk4 = *(const float4*)&wksT[ch * HD + wv * 4];
                const float4 wq4 = *(const float4*)&wqsT[ch * HD + wv * 4];
                #pragma unroll
                for (int eg = 0; eg < 2; ++eg) {
                    const int e2 = g * 2 + eg;
                    unsigned int u = xr[eg][ch >> 1];
                    float xv = (ch & 1) ? bfhi(u) : bflo(u);
                    float lnv = fmaf((xv - mu[e2]) * rs[e2], lw[ch], lb[ch]);
                    ka[eg][0] = fmaf(wk4.x, lnv, ka[eg][0]);
                    ka[eg][1] = fmaf(wk4.y, lnv, ka[eg][1]);
                    ka[eg][2] = fmaf(wk4.z, lnv, ka[eg][2]);
                    ka[eg][3] = fmaf(wk4.w, lnv, ka[eg][3]);
                    qa[eg][0] = fmaf(wq4.x, lnv, qa[eg][0]);
                    qa[eg][1] = fmaf(wq4.y, lnv, qa[eg][1]);
                    qa[eg][2] = fmaf(wq4.z, lnv, qa[eg][2]);
                    qa[eg][3] = fmaf(wq4.w, lnv, qa[eg][3]);
                }
            }
            #pragma unroll
            for (int eg = 0; eg < 2; ++eg) {
                const int e2 = g * 2 + eg;
                uint2 kp, qp;
                kp.x = f2bf(fmaxf(ka[eg][0], 0.f)) | (f2bf(fmaxf(ka[eg][1], 0.f)) << 16);
                kp.y = f2bf(fmaxf(ka[eg][2], 0.f)) | (f2bf(fmaxf(ka[eg][3], 0.f)) << 16);
                qp.x = f2bf(fmaxf(qa[eg][0], 0.f)) | (f2bf(fmaxf(qa[eg][1], 0.f)) << 16);
                qp.y = f2bf(fmaxf(qa[eg][2], 0.f)) | (f2bf(fmaxf(qa[eg][3], 0.f)) << 16);
                *(uint2*)&stage[lane][e2 * 8 + wv * 2] = kp;
                *(uint2*)&stage[lane][80 + e2 * 8 + wv * 2] = qp;
            }
        }
        __syncthreads();
        if (pr < 100) {
            #pragma unroll 8
            for (int p = 0; p < 64; ++p) {
                uint4 kk = *(const uint4*)&stage[p][pi * 8 + hf * 4];
                uint4 qq = *(const uint4*)&stage[p][80 + pj * 8 + hf * 4];
                acc[0] = fmaf(bflo(kk.x), bflo(qq.x), acc[0]);
                acc[1] = fmaf(bfhi(kk.x), bfhi(qq.x), acc[1]);
                acc[2] = fmaf(bflo(kk.y), bflo(qq.y), acc[2]);
                acc[3] = fmaf(bfhi(kk.y), bfhi(qq.y), acc[3]);
                acc[4] = fmaf(bflo(kk.z), bflo(qq.z), acc[4]);
                acc[5] = fmaf(bfhi(kk.z), bfhi(qq.z), acc[5]);
                acc[6] = fmaf(bflo(kk.w), bflo(qq.w), acc[6]);
                acc[7] = fmaf(bfhi(kk.w), bfhi(qq.w), acc[7]);
            }
        }
        __syncthreads();
    }
    if (pr < 100) {
        #pragma unroll
        for (int c2 = 0; c2 < 8; ++c2)
            atomicAdd(&sacc[((hf * 8 + c2) * EE + pi) * EE + pj], acc[c2]);
    }
}

// ---------------- softmax over i + fold A = delta + w - 1/E ----------------
__global__ void softmax_kernel(const float* __restrict__ sacc, float* __restrict__ A)
{
    int t = threadIdx.x;
    if (t >= HD * EE) return;
    int c = t / EE, j = t - c * EE;
    const float norm = (float)(1.0 / 509.8234988357398);  // 1/sqrt(361*720)
    float sv[EE];
    float mx = -1e30f;
    #pragma unroll
    for (int i = 0; i < EE; ++i) { sv[i] = sacc[(c * EE + i) * EE + j] * norm; mx = fmaxf(mx, sv[i]); }
    float sum = 0.f;
    #pragma unroll
    for (int i = 0; i < EE; ++i) { sv[i] = expf(sv[i] - mx); sum += sv[i]; }
    float inv = 1.f / sum;
    #pragma unroll
    for (int i = 0; i < EE; ++i) {
        float wgt = sv[i] * inv;
        A[(c * EE + i) * EE + j] = wgt - (1.f / (float)EE) + (i == j ? 1.f : 0.f);
    }
}

// ---------------- fused: v -> tv (via A) -> out proj + residual + relu -> y ----------------
// block 256 (4 waves), 128 pixels/block; lanes (l, l+32) pair on one pixel, 8 heads each.
// v staged in LDS bf16 [128][84 dwords].
__global__ __launch_bounds__(256) void final_kernel(
    const unsigned short* __restrict__ x, const float* __restrict__ ln_w,
    const float* __restrict__ ln_b, const float* __restrict__ wvw,
    const float* __restrict__ wo, const float* __restrict__ bo,
    const float* __restrict__ w_out, const float* __restrict__ b_out,
    const float* __restrict__ stats, const float* __restrict__ A,
    float* __restrict__ y)
{
    __shared__ unsigned int vst[128][84];   // 43 KB, bf16-packed v
    __shared__ float As[HD * EE * EE];      // [c][i][j]
    __shared__ float wvsT[CC * HD];         // [ch][c]
    __shared__ float wos[HD * CC];          // [c][ch] (transposed wo)
    __shared__ float bos[CC];
    __shared__ float wouts[CC];
    const int tid = threadIdx.x;
    for (int t = tid; t < CC * HD; t += 256) {
        int ch = t >> 4, c = t & 15;
        wvsT[t] = wvw[c * CC + ch];
        wos[c * CC + ch] = wo[ch * HD + c];
    }
    for (int t = tid; t < HD * EE * EE; t += 256) As[t] = A[t];
    if (tid < CC) { bos[tid] = bo[tid]; wouts[tid] = w_out[tid]; }
    __syncthreads();

    const int wvi = tid >> 6, lane = tid & 63;
    const int lpx = lane & 31, hf = lane >> 5;
    const int mypx = wvi * 32 + lpx;
    const int pix = blockIdx.x * 128 + mypx;
    const bool valid = pix < HWP;

    float mu[EE], rs[EE];
    #pragma unroll
    for (int e2 = 0; e2 < EE; ++e2) { mu[e2] = stats[2 * EE + e2]; rs[e2] = stats[3 * EE + e2]; }

    {
        float lw[CC], lb[CC];
        #pragma unroll
        for (int ch = 0; ch < CC; ++ch) {
            lw[ch] = valid ? ln_w[(size_t)ch * HWP + pix] : 0.f;
            lb[ch] = valid ? ln_b[(size_t)ch * HWP + pix] : 0.f;
        }
        float cb0[8], cb1[8];
        #pragma unroll
        for (int cc = 0; cc < 8; ++cc) { cb0[cc] = 0.f; cb1[cc] = 0.f; }
        #pragma unroll
        for (int ch = 0; ch < CC; ++ch) {
            const float4 w0 = *(const float4*)&wvsT[ch * HD + hf * 8];
            const float4 w1 = *(const float4*)&wvsT[ch * HD + hf * 8 + 4];
            cb1[0] = fmaf(w0.x, lw[ch], cb1[0]); cb1[1] = fmaf(w0.y, lw[ch], cb1[1]);
            cb1[2] = fmaf(w0.z, lw[ch], cb1[2]); cb1[3] = fmaf(w0.w, lw[ch], cb1[3]);
            cb1[4] = fmaf(w1.x, lw[ch], cb1[4]); cb1[5] = fmaf(w1.y, lw[ch], cb1[5]);
            cb1[6] = fmaf(w1.z, lw[ch], cb1[6]); cb1[7] = fmaf(w1.w, lw[ch], cb1[7]);
            cb0[0] = fmaf(w0.x, lb[ch], cb0[0]); cb0[1] = fmaf(w0.y, lb[ch], cb0[1]);
            cb0[2] = fmaf(w0.z, lb[ch], cb0[2]); cb0[3] = fmaf(w0.w, lb[ch], cb0[3]);
            cb0[4] = fmaf(w1.x, lb[ch], cb0[4]); cb0[5] = fmaf(w1.y, lb[ch], cb0[5]);
            cb0[6] = fmaf(w1.z, lb[ch], cb0[6]); cb0[7] = fmaf(w1.w, lb[ch], cb0[7]);
        }
        #pragma unroll 1
        for (int g = 0; g < 5; ++g) {
            unsigned int xr[2][16];
            #pragma unroll
            for (int eg = 0; eg < 2; ++eg) {
                const int e2 = g * 2 + eg;
                if (valid) {
                    const uint4* xp = (const uint4*)(x + ((size_t)e2 * HWP + pix) * CC);
                    uint4 a0 = xp[0], a1 = xp[1], a2 = xp[2], a3 = xp[3];
                    xr[eg][0]=a0.x; xr[eg][1]=a0.y; xr[eg][2]=a0.z; xr[eg][3]=a0.w;
                    xr[eg][4]=a1.x; xr[eg][5]=a1.y; xr[eg][6]=a1.z; xr[eg][7]=a1.w;
                    xr[eg][8]=a2.x; xr[eg][9]=a2.y; xr[eg][10]=a2.z; xr[eg][11]=a2.w;
                    xr[eg][12]=a3.x; xr[eg][13]=a3.y; xr[eg][14]=a3.z; xr[eg][15]=a3.w;
                } else {
                    #pragma unroll
                    for (int k2 = 0; k2 < 16; ++k2) xr[eg][k2] = 0u;
                }
            }
            float a[2][8];
            #pragma unroll
            for (int eg = 0; eg < 2; ++eg)
                #pragma unroll
                for (int cc = 0; cc < 8; ++cc) a[eg][cc] = 0.f;
            #pragma unroll
            for (int ch = 0; ch < CC; ++ch) {
                const float lwc = lw[ch];
                const float4 w0 = *(const float4*)&wvsT[ch * HD + hf * 8];
                const float4 w1 = *(const float4*)&wvsT[ch * HD + hf * 8 + 4];
                #pragma unroll
                for (int eg = 0; eg < 2; ++eg) {
                    unsigned int u = xr[eg][ch >> 1];
                    float t2 = ((ch & 1) ? bfhi(u) : bflo(u)) * lwc;
                    a[eg][0] = fmaf(w0.x, t2, a[eg][0]); a[eg][1] = fmaf(w0.y, t2, a[eg][1]);
                    a[eg][2] = fmaf(w0.z, t2, a[eg][2]); a[eg][3] = fmaf(w0.w, t2, a[eg][3]);
                    a[eg][4] = fmaf(w1.x, t2, a[eg][4]); a[eg][5] = fmaf(w1.y, t2, a[eg][5]);
                    a[eg][6] = fmaf(w1.z, t2, a[eg][6]); a[eg][7] = fmaf(w1.w, t2, a[eg][7]);
                }
            }
            #pragma unroll
            for (int eg = 0; eg < 2; ++eg) {
                const int e2 = g * 2 + eg;
                unsigned int vp[4];
                #pragma unroll
                for (int cc = 0; cc < 8; cc += 2) {
                    float v0 = rs[e2] * a[eg][cc]     - mu[e2] * rs[e2] * cb1[cc]     + cb0[cc];
                    float v1 = rs[e2] * a[eg][cc + 1] - mu[e2] * rs[e2] * cb1[cc + 1] + cb0[cc + 1];
                    vp[cc >> 1] = f2bf(v0) | (f2bf(v1) << 16);
                }
                *(uint4*)&vst[mypx][e2 * 8 + hf * 4] = make_uint4(vp[0], vp[1], vp[2], vp[3]);
            }
        }
    }
    __syncthreads();

    const float boutv = b_out[0];
    #pragma unroll 1
    for (int j = 0; j < EE; ++j) {
        float ar[EE][8];
        #pragma unroll
        for (int i = 0; i < EE; ++i)
            #pragma unroll
            for (int cc = 0; cc < 8; ++cc)
                ar[i][cc] = As[((hf * 8 + cc) * EE + i) * EE + j];
        float tv[8];
        #pragma unroll
        for (int cc = 0; cc < 8; ++cc) tv[cc] = 0.f;
        #pragma unroll
        for (int i = 0; i < EE; ++i) {
            uint4 vv = *(const uint4*)&vst[mypx][i * 8 + hf * 4];
            tv[0] = fmaf(bflo(vv.x), ar[i][0], tv[0]);
            tv[1] = fmaf(bfhi(vv.x), ar[i][1], tv[1]);
            tv[2] = fmaf(bflo(vv.y), ar[i][2], tv[2]);
            tv[3] = fmaf(bfhi(vv.y), ar[i][3], tv[3]);
            tv[4] = fmaf(bflo(vv.z), ar[i][4], tv[4]);
            tv[5] = fmaf(bfhi(vv.z), ar[i][5], tv[5]);
            tv[6] = fmaf(bflo(vv.w), ar[i][6], tv[6]);
            tv[7] = fmaf(bfhi(vv.w), ar[i][7], tv[7]);
        }
        unsigned int xj[16];
        if (valid) {
            const uint4* xp = (const uint4*)(x + ((size_t)j * HWP + pix) * CC);
            uint4 a0 = xp[0], a1 = xp[1], a2 = xp[2], a3 = xp[3];
            xj[0]=a0.x; xj[1]=a0.y; xj[2]=a0.z; xj[3]=a0.w;
            xj[4]=a1.x; xj[5]=a1.y; xj[6]=a1.z; xj[7]=a1.w;
            xj[8]=a2.x; xj[9]=a2.y; xj[10]=a2.z; xj[11]=a2.w;
            xj[12]=a3.x; xj[13]=a3.y; xj[14]=a3.z; xj[15]=a3.w;
        } else {
            #pragma unroll
            for (int k2 = 0; k2 < 16; ++k2) xj[k2] = 0u;
        }
        float o[CC];
        #pragma unroll
        for (int ch = 0; ch < CC; ++ch) {
            unsigned int u = xj[ch >> 1];
            float xv = (ch & 1) ? bfhi(u) : bflo(u);
            o[ch] = hf ? 0.f : (bos[ch] + xv);
        }
        #pragma unroll
        for (int cc = 0; cc < 8; ++cc) {
            const float tvc = tv[cc];
            const float* wcol = &wos[(hf * 8 + cc) * CC];
            #pragma unroll
            for (int ch = 0; ch < CC; ++ch) o[ch] = fmaf(wcol[ch], tvc, o[ch]);
        }
        float yv = 0.f;
        #pragma unroll
        for (int ch = 0; ch < CC; ++ch) {
            float of = o[ch] + __shfl_xor(o[ch], 32);
            if ((ch >> 4) == hf) yv = fmaf(wouts[ch], fmaxf(of, 0.f), yv);
        }
        yv += __shfl_xor(yv, 32);
        if (hf == 0 && valid) y[(size_t)j * HWP + pix] = yv + boutv;
    }
}

extern "C" void kernel_launch(void* const* d_in, const int* in_sizes, int n_in,
                              void* d_out, int out_size, void* d_ws, size_t ws_size,
                              hipStream_t stream)
{
    const float* inp   = (const float*)d_in[0];
    const float* emb_w = (const float*)d_in[1];
    const float* emb_b = (const float*)d_in[2];
    const float* ln_w  = (const float*)d_in[3];
    const float* ln_b  = (const float*)d_in[4];
    const float* wv    = (const float*)d_in[5];
    const float* wk    = (const float*)d_in[6];
    const float* wq    = (const float*)d_in[7];
    const float* wo    = (const float*)d_in[8];
    const float* bo    = (const float*)d_in[9];
    const float* w_out = (const float*)d_in[10];
    const float* b_out = (const float*)d_in[11];
    float* y = (float*)d_out;

    // ws: x bf16 channel-last [E][HW][32] = 166,348,800 B; then stats(40)+sacc(1600)+A(1600)
    unsigned short* xbuf = (unsigned short*)d_ws;
    float* stats = (float*)((char*)d_ws + (size_t)EE * HWP * CC * 2);
    float* sacc  = stats + 40;
    float* Amat  = sacc + HD * EE * EE;

    zero_kernel<<<7, 256, 0, stream>>>(stats);
    conv_selu_kernel<<<dim3(12, 91, EE), dim3(64, 4), 0, stream>>>(inp, emb_w, emb_b, xbuf, stats);
    ln_stats_kernel<<<1, 64, 0, stream>>>(stats);
    scores_fused_kernel<<<1024, 256, 0, stream>>>(xbuf, ln_w, ln_b, wk, wq, stats, sacc);
    softmax_kernel<<<1, 192, 0, stream>>>(sacc, Amat);
    final_kernel<<<(HWP + 127) / 128, 256, 0, stream>>>(xbuf, ln_w, ln_b, wv, wo, bo,
                                                        w_out, b_out, stats, Amat, y);
}